// Round 3
// baseline (1003.662 us; speedup 1.0000x reference)
//
#include <hip/hip_runtime.h>

// Problem constants (fixed by reference setup_inputs)
constexpr int T_DIM = 10, C_DIM = 3, H_DIM = 512, W_DIM = 512;
constexpr int PT = 2, PS = 7;
constexpr int ELEM_PER_Q = PT * C_DIM * PS * PS;  // 294
constexpr int HALF      = C_DIM * PS * PS;        // 147 (one dt-slice of a patch)
constexpr int TILE = 38;                           // anchor bin & output tile (h,w)
constexpr int NBH = 14, NBW = 14;                  // ceil(506/38)=14
constexpr int NTB = T_DIM - PT + 1;                // 9 anchor t values
constexpr int NBINS = NTB * NBH * NBW;             // 1764
constexpr int BINPAD = 2048;
constexpr int HTILE = TILE + PS - 1;               // 44: tile + down-right halo
constexpr int ACC_SLICE = C_DIM * HTILE * HTILE;   // 5808 floats per t-slice
constexpr int NPAIR = T_DIM / 2;                   // 5 t-pairs
constexpr int STRIDE_F = 304;                      // reorder chunk: 294 payload + 1 meta + pad
                                                   // 304*4 = 1216 B = 19 cache lines, 64B-aligned

// ws layout (reorder path): counts[2048] | offsets[2048] | cursors[2048] |
//   posOf[Q] | (256B-aligned) reord[Q*304 floats]
// ws layout (fallback):     counts | offsets | cursors | list[Q]

__global__ __launch_bounds__(256) void ScatterNL_hist(
    const int* __restrict__ qinds, int Q, int* __restrict__ counts)
{
    __shared__ int hloc[NBINS];
    for (int i = threadIdx.x; i < NBINS; i += blockDim.x) hloc[i] = 0;
    __syncthreads();
    int stride = gridDim.x * blockDim.x;
    for (int q = blockIdx.x * blockDim.x + threadIdx.x; q < Q; q += stride) {
        int t = qinds[3*q], h = qinds[3*q+1], w = qinds[3*q+2];
        int b = (t * NBH + h / TILE) * NBW + w / TILE;
        atomicAdd(&hloc[b], 1);
    }
    __syncthreads();
    for (int i = threadIdx.x; i < NBINS; i += blockDim.x)
        if (hloc[i]) atomicAdd(&counts[i], hloc[i]);
}

// 256 threads, each owns 7 consecutive bins (256*7=1792 >= 1764).
__global__ __launch_bounds__(256) void ScatterNL_scan(
    const int* __restrict__ counts, int* __restrict__ offsets,
    int* __restrict__ cursors)
{
    __shared__ int buf[2][256];
    int tid = threadIdx.x;
    int base = tid * 7;
    int loc[7];
    int s = 0;
    #pragma unroll
    for (int i = 0; i < 7; ++i) {
        int b = base + i;
        int v = (b < NBINS) ? counts[b] : 0;
        loc[i] = s;
        s += v;
    }
    buf[0][tid] = s;
    __syncthreads();
    int src = 0;
    for (int d = 1; d < 256; d <<= 1) {
        int x = buf[src][tid] + ((tid >= d) ? buf[src][tid - d] : 0);
        buf[src ^ 1][tid] = x;
        __syncthreads();
        src ^= 1;
    }
    int excl = (tid == 0) ? 0 : buf[src][tid - 1];
    #pragma unroll
    for (int i = 0; i < 7; ++i) {
        int b = base + i;
        if (b < NBINS) {
            offsets[b] = excl + loc[i];
            cursors[b] = excl + loc[i];
        }
    }
    if (tid == 255) offsets[NBINS] = buf[src][255];
}

// Reorder path: only coalesced posOf[q] write (no scattered list write).
__global__ __launch_bounds__(256) void ScatterNL_fillPos(
    const int* __restrict__ qinds, int Q, int* __restrict__ cursors,
    int* __restrict__ posOf)
{
    int stride = gridDim.x * blockDim.x;
    for (int q = blockIdx.x * blockDim.x + threadIdx.x; q < Q; q += stride) {
        int t = qinds[3*q], h = qinds[3*q+1], w = qinds[3*q+2];
        int b = (t * NBH + h / TILE) * NBW + w / TILE;
        posOf[q] = atomicAdd(&cursors[b], 1);
    }
}

// Sequential patch read, scatter-write of contiguous 1216B chunks to
// bin-sorted slots. meta (dh|dw<<6) embedded at float index 294.
__global__ __launch_bounds__(256) void ScatterNL_reorder(
    const float* __restrict__ patches, const int* __restrict__ qinds,
    const int* __restrict__ posOf, int Q, float* __restrict__ reord)
{
    int gw   = (blockIdx.x * blockDim.x + threadIdx.x) >> 6;
    int lane = threadIdx.x & 63;
    int nw   = (gridDim.x * blockDim.x) >> 6;
    const bool tail = (lane < ELEM_PER_Q - 256);   // lane < 38
    for (int q0 = 2 * gw; q0 < Q; q0 += 2 * nw) {
        bool two = (q0 + 1 < Q);
        int p0 = posOf[q0];
        int p1 = two ? posOf[q0 + 1] : p0;
        int h0 = qinds[3*q0+1], w0 = qinds[3*q0+2];
        int h1 = two ? qinds[3*q0+4] : 0, w1 = two ? qinds[3*q0+5] : 0;
        const float* s0 = patches + (size_t)q0 * ELEM_PER_Q;
        const float* s1 = s0 + ELEM_PER_Q;
        float a0 = s0[lane], a1 = s0[lane+64], a2 = s0[lane+128], a3 = s0[lane+192];
        float a4 = tail ? s0[lane+256] : 0.f;
        float b0 = 0.f, b1 = 0.f, b2 = 0.f, b3 = 0.f, b4 = 0.f;
        if (two) {
            b0 = s1[lane]; b1 = s1[lane+64]; b2 = s1[lane+128]; b3 = s1[lane+192];
            b4 = tail ? s1[lane+256] : 0.f;
        }
        __builtin_amdgcn_sched_barrier(0);         // keep load cluster together
        float* d0 = reord + (size_t)p0 * STRIDE_F;
        d0[lane] = a0; d0[lane+64] = a1; d0[lane+128] = a2; d0[lane+192] = a3;
        if (tail) d0[lane+256] = a4;
        if (lane == 0)
            d0[294] = __int_as_float((h0 % TILE) | ((w0 % TILE) << 6));
        if (two) {
            float* d1 = reord + (size_t)p1 * STRIDE_F;
            d1[lane] = b0; d1[lane+64] = b1; d1[lane+128] = b2; d1[lane+192] = b3;
            if (tail) d1[lane+256] = b4;
            if (lane == 0)
                d1[294] = __int_as_float((h1 % TILE) | ((w1 % TILE) << 6));
        }
    }
}

// out = vid (accum then atomically adds patch contributions)
__global__ __launch_bounds__(256) void ScatterNL_copy(
    const float* __restrict__ vid, float* __restrict__ out, int n4)
{
    int stride = gridDim.x * blockDim.x;
    const float4* src = (const float4*)vid;
    float4* dst = (float4*)out;
    for (int i = blockIdx.x * blockDim.x + threadIdx.x; i < n4; i += stride)
        dst[i] = src[i];
}

// Pass 2: identical halo-LDS structure to R2, but all reads are SEQUENTIAL
// sweeps of the bin-sorted reord buffer.
__global__ __launch_bounds__(512, 6) void ScatterNL_accum2(
    const float* __restrict__ reord, const int* __restrict__ offsets,
    float* __restrict__ out)
{
    __shared__ float acc[2 * ACC_SLICE];           // 46,464 B -> 3 blocks/CU

    int bid = blockIdx.x;
    int k   = bid / (NBH * NBW);                   // t-pair 0..4
    int r   = bid % (NBH * NBW);
    int bh  = r / NBW, bw = r % NBW;
    int h0  = bh * TILE, w0 = bw * TILE;

    for (int i = threadIdx.x; i < 2 * ACC_SLICE; i += blockDim.x)
        acc[i] = 0.f;
    __syncthreads();

    const int lane = threadIdx.x & 63;
    const int wv   = threadIdx.x >> 6;             // 0..7

    int off3[3];
    #pragma unroll
    for (int s = 0; s < 3; ++s) {
        int kx = lane + 64 * s;
        int kk = (kx < HALF) ? kx : 0;
        int c = kk / 49, rr = kk % 49;
        off3[s] = (c * HTILE + rr / 7) * HTILE + rr % 7;
    }
    const bool v2ok = (lane < HALF - 128);         // lane < 19
    int offf[5];
    #pragma unroll
    for (int s = 0; s < 5; ++s) {
        int kx = lane + 64 * s;
        int kk = (kx < ELEM_PER_Q) ? kx : 0;
        int sl = kk / HALF;
        int rem = kk % HALF;
        int c = rem / 49, rr = rem % 49;
        offf[s] = sl * ACC_SLICE + (c * HTILE + rr / 7) * HTILE + rr % 7;
    }
    const bool v4ok = (lane < ELEM_PER_Q - 256);   // lane < 38

    // ---- full-patch bin (tb = 2k), depth-2 ----
    {
        int bin = (2 * k * NBH + bh) * NBW + bw;
        int start = offsets[bin], n = offsets[bin + 1] - start;
        for (int base = wv * 2; base < n; base += 16) {
            int nb = n - base;
            const float* P0 = reord + (size_t)(start + base) * STRIDE_F;
            const float* P1 = (nb > 1) ? P0 + STRIDE_F : P0;
            float a0[5], a1[5];
            #pragma unroll
            for (int s = 0; s < 5; ++s) {
                bool v = (s < 4) || v4ok;
                a0[s] = v ? P0[lane + 64*s] : 0.f;
                a1[s] = v ? P1[lane + 64*s] : 0.f;
            }
            int m0 = __float_as_int(P0[294]);
            int m1 = __float_as_int(P1[294]);
            __builtin_amdgcn_sched_barrier(0);
            int d0 = (m0 & 63) * HTILE + ((m0 >> 6) & 63);
            int d1 = (m1 & 63) * HTILE + ((m1 >> 6) & 63);
            #pragma unroll
            for (int s = 0; s < 5; ++s)
                if ((s < 4) || v4ok) atomicAdd(&acc[d0 + offf[s]], a0[s]);
            if (nb > 1) {
                #pragma unroll
                for (int s = 0; s < 5; ++s)
                    if ((s < 4) || v4ok) atomicAdd(&acc[d1 + offf[s]], a1[s]);
            }
        }
    }

    // ---- half-patch bins, depth-4 ----
    auto procHalf = [&](int bin, int dtOff, int ss) {
        int start = offsets[bin], n = offsets[bin + 1] - start;
        int sbase = ss * ACC_SLICE;
        for (int base = wv * 4; base < n; base += 32) {
            int nb = n - base;
            const float* P0 = reord + (size_t)(start + base) * STRIDE_F;
            const float* P1 = (nb > 1) ? P0 + STRIDE_F     : P0;
            const float* P2 = (nb > 2) ? P0 + 2*STRIDE_F   : P0;
            const float* P3 = (nb > 3) ? P0 + 3*STRIDE_F   : P0;
            float a00 = P0[dtOff+lane], a01 = P0[dtOff+lane+64], a02 = v2ok ? P0[dtOff+lane+128] : 0.f;
            float a10 = P1[dtOff+lane], a11 = P1[dtOff+lane+64], a12 = v2ok ? P1[dtOff+lane+128] : 0.f;
            float a20 = P2[dtOff+lane], a21 = P2[dtOff+lane+64], a22 = v2ok ? P2[dtOff+lane+128] : 0.f;
            float a30 = P3[dtOff+lane], a31 = P3[dtOff+lane+64], a32 = v2ok ? P3[dtOff+lane+128] : 0.f;
            int m0 = __float_as_int(P0[294]);
            int m1 = __float_as_int(P1[294]);
            int m2 = __float_as_int(P2[294]);
            int m3 = __float_as_int(P3[294]);
            __builtin_amdgcn_sched_barrier(0);
            int d0 = sbase + (m0 & 63) * HTILE + ((m0 >> 6) & 63);
            int d1 = sbase + (m1 & 63) * HTILE + ((m1 >> 6) & 63);
            int d2 = sbase + (m2 & 63) * HTILE + ((m2 >> 6) & 63);
            int d3 = sbase + (m3 & 63) * HTILE + ((m3 >> 6) & 63);
            atomicAdd(&acc[d0 + off3[0]], a00);
            atomicAdd(&acc[d0 + off3[1]], a01);
            if (v2ok) atomicAdd(&acc[d0 + off3[2]], a02);
            if (nb > 1) {
                atomicAdd(&acc[d1 + off3[0]], a10);
                atomicAdd(&acc[d1 + off3[1]], a11);
                if (v2ok) atomicAdd(&acc[d1 + off3[2]], a12);
            }
            if (nb > 2) {
                atomicAdd(&acc[d2 + off3[0]], a20);
                atomicAdd(&acc[d2 + off3[1]], a21);
                if (v2ok) atomicAdd(&acc[d2 + off3[2]], a22);
            }
            if (nb > 3) {
                atomicAdd(&acc[d3 + off3[0]], a30);
                atomicAdd(&acc[d3 + off3[1]], a31);
                if (v2ok) atomicAdd(&acc[d3 + off3[2]], a32);
            }
        }
    };
    if (2 * k + 1 <= T_DIM - PT)
        procHalf(((2 * k + 1) * NBH + bh) * NBW + bw, 0, 1);    // dt=0 -> slice 1
    if (2 * k - 1 >= 0)
        procHalf(((2 * k - 1) * NBH + bh) * NBW + bw, HALF, 0); // dt=1 -> slice 0

    __syncthreads();

    int He = min(HTILE, H_DIM - h0);
    int We = min(HTILE, W_DIM - w0);
    for (int ls = 0; ls < 2; ++ls) {
        int ts = 2 * k + ls;
        #pragma unroll
        for (int c = 0; c < C_DIM; ++c) {
            for (int y = wv; y < He; y += 8) {
                if (lane < We) {
                    float v = acc[(ls * C_DIM + c) * HTILE * HTILE + y * HTILE + lane];
                    size_t o = (((size_t)ts * C_DIM + c) * H_DIM + (h0 + y)) * W_DIM + w0 + lane;
                    atomicAdd(&out[o], v);
                }
            }
        }
    }
}

// ---------------- Fallback path (R2, proven) for small ws_size ----------------

__global__ __launch_bounds__(256) void ScatterNL_fillList(
    const int* __restrict__ qinds, int Q, int* __restrict__ cursors,
    int* __restrict__ list)
{
    int stride = gridDim.x * blockDim.x;
    for (int q = blockIdx.x * blockDim.x + threadIdx.x; q < Q; q += stride) {
        int t = qinds[3*q], h = qinds[3*q+1], w = qinds[3*q+2];
        int sh = h / TILE, sw = w / TILE;
        int b = (t * NBH + sh) * NBW + sw;
        int pos = atomicAdd(&cursors[b], 1);
        list[pos] = q | ((h - sh * TILE) << 18) | ((w - sw * TILE) << 24);
    }
}

__global__ __launch_bounds__(512, 6) void ScatterNL_accumList(
    const float* __restrict__ patches, const int* __restrict__ offsets,
    const int* __restrict__ list, float* __restrict__ out)
{
    __shared__ float acc[2 * ACC_SLICE];
    int bid = blockIdx.x;
    int k   = bid / (NBH * NBW);
    int r   = bid % (NBH * NBW);
    int bh  = r / NBW, bw = r % NBW;
    int h0  = bh * TILE, w0 = bw * TILE;
    for (int i = threadIdx.x; i < 2 * ACC_SLICE; i += blockDim.x) acc[i] = 0.f;
    __syncthreads();
    const int lane = threadIdx.x & 63;
    const int wv   = threadIdx.x >> 6;
    int off3[3];
    #pragma unroll
    for (int s = 0; s < 3; ++s) {
        int kx = lane + 64 * s;
        int kk = (kx < HALF) ? kx : 0;
        int c = kk / 49, rr = kk % 49;
        off3[s] = (c * HTILE + rr / 7) * HTILE + rr % 7;
    }
    const bool v2ok = (lane < HALF - 128);
    int offf[5];
    #pragma unroll
    for (int s = 0; s < 5; ++s) {
        int kx = lane + 64 * s;
        int kk = (kx < ELEM_PER_Q) ? kx : 0;
        int sl = kk / HALF;
        int rem = kk % HALF;
        int c = rem / 49, rr = rem % 49;
        offf[s] = sl * ACC_SLICE + (c * HTILE + rr / 7) * HTILE + rr % 7;
    }
    const bool v4ok = (lane < ELEM_PER_Q - 256);
    auto procHalf = [&](int bin, int dtOff, int ss) {
        int start = offsets[bin], n = offsets[bin + 1] - start;
        int sbase = ss * ACC_SLICE;
        for (int base = wv * 4; base < n; base += 32) {
            int i0 = start + base;
            int nb = n - base;
            int e0 = list[i0];
            int e1 = (nb > 1) ? list[i0 + 1] : e0;
            int e2 = (nb > 2) ? list[i0 + 2] : e0;
            int e3 = (nb > 3) ? list[i0 + 3] : e0;
            const float* B0 = patches + (size_t)(e0 & 0x3FFFF) * ELEM_PER_Q + dtOff;
            const float* B1 = patches + (size_t)(e1 & 0x3FFFF) * ELEM_PER_Q + dtOff;
            const float* B2 = patches + (size_t)(e2 & 0x3FFFF) * ELEM_PER_Q + dtOff;
            const float* B3 = patches + (size_t)(e3 & 0x3FFFF) * ELEM_PER_Q + dtOff;
            float a00 = B0[lane], a01 = B0[lane+64], a02 = v2ok ? B0[lane+128] : 0.f;
            float a10 = B1[lane], a11 = B1[lane+64], a12 = v2ok ? B1[lane+128] : 0.f;
            float a20 = B2[lane], a21 = B2[lane+64], a22 = v2ok ? B2[lane+128] : 0.f;
            float a30 = B3[lane], a31 = B3[lane+64], a32 = v2ok ? B3[lane+128] : 0.f;
            __builtin_amdgcn_sched_barrier(0);
            int d0 = sbase + ((e0 >> 18) & 63) * HTILE + ((e0 >> 24) & 63);
            int d1 = sbase + ((e1 >> 18) & 63) * HTILE + ((e1 >> 24) & 63);
            int d2 = sbase + ((e2 >> 18) & 63) * HTILE + ((e2 >> 24) & 63);
            int d3 = sbase + ((e3 >> 18) & 63) * HTILE + ((e3 >> 24) & 63);
            atomicAdd(&acc[d0 + off3[0]], a00);
            atomicAdd(&acc[d0 + off3[1]], a01);
            if (v2ok) atomicAdd(&acc[d0 + off3[2]], a02);
            if (nb > 1) {
                atomicAdd(&acc[d1 + off3[0]], a10);
                atomicAdd(&acc[d1 + off3[1]], a11);
                if (v2ok) atomicAdd(&acc[d1 + off3[2]], a12);
            }
            if (nb > 2) {
                atomicAdd(&acc[d2 + off3[0]], a20);
                atomicAdd(&acc[d2 + off3[1]], a21);
                if (v2ok) atomicAdd(&acc[d2 + off3[2]], a22);
            }
            if (nb > 3) {
                atomicAdd(&acc[d3 + off3[0]], a30);
                atomicAdd(&acc[d3 + off3[1]], a31);
                if (v2ok) atomicAdd(&acc[d3 + off3[2]], a32);
            }
        }
    };
    {
        int bin = (2 * k * NBH + bh) * NBW + bw;
        int start = offsets[bin], n = offsets[bin + 1] - start;
        for (int base = wv * 2; base < n; base += 16) {
            int i0 = start + base;
            int nb = n - base;
            int e0 = list[i0];
            int e1 = (nb > 1) ? list[i0 + 1] : e0;
            const float* B0 = patches + (size_t)(e0 & 0x3FFFF) * ELEM_PER_Q;
            const float* B1 = patches + (size_t)(e1 & 0x3FFFF) * ELEM_PER_Q;
            float a0[5], a1[5];
            #pragma unroll
            for (int s = 0; s < 5; ++s) {
                bool v = (s < 4) || v4ok;
                a0[s] = v ? B0[lane + 64*s] : 0.f;
                a1[s] = v ? B1[lane + 64*s] : 0.f;
            }
            __builtin_amdgcn_sched_barrier(0);
            int d0 = ((e0 >> 18) & 63) * HTILE + ((e0 >> 24) & 63);
            int d1 = ((e1 >> 18) & 63) * HTILE + ((e1 >> 24) & 63);
            #pragma unroll
            for (int s = 0; s < 5; ++s)
                if ((s < 4) || v4ok) atomicAdd(&acc[d0 + offf[s]], a0[s]);
            if (nb > 1) {
                #pragma unroll
                for (int s = 0; s < 5; ++s)
                    if ((s < 4) || v4ok) atomicAdd(&acc[d1 + offf[s]], a1[s]);
            }
        }
    }
    if (2 * k + 1 <= T_DIM - PT)
        procHalf(((2 * k + 1) * NBH + bh) * NBW + bw, 0, 1);
    if (2 * k - 1 >= 0)
        procHalf(((2 * k - 1) * NBH + bh) * NBW + bw, HALF, 0);
    __syncthreads();
    int He = min(HTILE, H_DIM - h0);
    int We = min(HTILE, W_DIM - w0);
    for (int ls = 0; ls < 2; ++ls) {
        int ts = 2 * k + ls;
        #pragma unroll
        for (int c = 0; c < C_DIM; ++c) {
            for (int y = wv; y < He; y += 8) {
                if (lane < We) {
                    float v = acc[(ls * C_DIM + c) * HTILE * HTILE + y * HTILE + lane];
                    size_t o = (((size_t)ts * C_DIM + c) * H_DIM + (h0 + y)) * W_DIM + w0 + lane;
                    atomicAdd(&out[o], v);
                }
            }
        }
    }
}

extern "C" void kernel_launch(void* const* d_in, const int* in_sizes, int n_in,
                              void* d_out, int out_size, void* d_ws, size_t ws_size,
                              hipStream_t stream) {
    const float* vid     = (const float*)d_in[0];
    const float* patches = (const float*)d_in[1];
    const int*   qinds   = (const int*)d_in[2];
    float* out = (float*)d_out;
    int Q = in_sizes[2] / 3;

    int* ws      = (int*)d_ws;
    int* counts  = ws;
    int* offsets = ws + BINPAD;
    int* cursors = ws + 2 * BINPAD;
    int* slot    = ws + 3 * BINPAD;                // posOf[Q] or list[Q]

    size_t metaBytes = ((size_t)(3 * BINPAD) + (size_t)Q) * sizeof(int);
    size_t reordOff  = (metaBytes + 255) & ~(size_t)255;
    size_t need      = reordOff + (size_t)Q * STRIDE_F * sizeof(float);

    hipMemsetAsync(counts, 0, BINPAD * sizeof(int), stream);  // ws poisoned each call
    ScatterNL_copy<<<1024, 256, 0, stream>>>(vid, out,
        T_DIM * C_DIM * H_DIM * W_DIM / 4);
    ScatterNL_hist<<<256, 256, 0, stream>>>(qinds, Q, counts);
    ScatterNL_scan<<<1, 256, 0, stream>>>(counts, offsets, cursors);

    if (ws_size >= need) {
        float* reord = (float*)((char*)d_ws + reordOff);
        ScatterNL_fillPos<<<256, 256, 0, stream>>>(qinds, Q, cursors, slot);
        ScatterNL_reorder<<<2048, 256, 0, stream>>>(patches, qinds, slot, Q, reord);
        ScatterNL_accum2<<<NPAIR * NBH * NBW, 512, 0, stream>>>(reord, offsets, out);
    } else {
        ScatterNL_fillList<<<256, 256, 0, stream>>>(qinds, Q, cursors, slot);
        ScatterNL_accumList<<<NPAIR * NBH * NBW, 512, 0, stream>>>(
            patches, offsets, slot, out);
    }
}

// Round 4
// 915.770 us; speedup vs baseline: 1.0960x; 1.0960x over previous
//
#include <hip/hip_runtime.h>

// Problem constants (fixed by reference setup_inputs)
constexpr int T_DIM = 10, C_DIM = 3, H_DIM = 512, W_DIM = 512;
constexpr int PT = 2, PS = 7;
constexpr int ELEM_PER_Q = PT * C_DIM * PS * PS;  // 294
constexpr int HALF      = C_DIM * PS * PS;        // 147 (one dt-slice of a patch)
constexpr int TILE = 38;                           // anchor bin & output tile (h,w)
constexpr int NBH = 14, NBW = 14;                  // ceil(506/38)=14
constexpr int NTB = T_DIM - PT + 1;                // 9 anchor t values
constexpr int NBINS = NTB * NBH * NBW;             // 1764
constexpr int BINPAD = 2048;
constexpr int HTILE = TILE + PS - 1;               // 44: tile + down-right halo
constexpr int ACC_SLICE = C_DIM * HTILE * HTILE;   // (fallback path)
constexpr int NPAIR = T_DIM / 2;                   // 5 t-pairs
constexpr int STRIDE_F = 304;                      // reorder chunk floats (294+meta+pad)
constexpr int NCELL = NBINS * TILE;                // 67032 (bin, dh) cells
constexpr int CELLPAD = 67136;                     // padded cell-table stride (ints)

// ws layout (gather path): counts2[CELLPAD] | offsets2[CELLPAD] | cursors2[CELLPAD] |
//   posOf[Q] | (256B-aligned) reord[Q*304 floats]
// ws layout (fallback):    counts[2048] | offsets[2048] | cursors[2048] | list[Q]

// ---------------- two-level (bin,dh) histogram / scan / fill ----------------

__global__ __launch_bounds__(256) void ScatterNL_hist2(
    const int* __restrict__ qinds, int Q, int* __restrict__ counts2)
{
    int stride = gridDim.x * blockDim.x;
    for (int q = blockIdx.x * blockDim.x + threadIdx.x; q < Q; q += stride) {
        int t = qinds[3*q], h = qinds[3*q+1], w = qinds[3*q+2];
        int sh = h / TILE, sw = w / TILE;
        int cell = ((t * NBH + sh) * NBW + sw) * TILE + (h - sh * TILE);
        atomicAdd(&counts2[cell], 1);
    }
}

// One block, 256 threads, each owns 262 consecutive cells (256*262 >= 67032).
__global__ __launch_bounds__(256) void ScatterNL_scan2(
    const int* __restrict__ counts2, int* __restrict__ offsets2,
    int* __restrict__ cursors2)
{
    constexpr int CPB = 262;
    __shared__ int buf[2][256];
    int tid = threadIdx.x;
    int base = tid * CPB;
    int s = 0;
    for (int i = 0; i < CPB; ++i) {
        int b = base + i;
        s += (b < NCELL) ? counts2[b] : 0;
    }
    buf[0][tid] = s;
    __syncthreads();
    int src = 0;
    for (int d = 1; d < 256; d <<= 1) {
        int x = buf[src][tid] + ((tid >= d) ? buf[src][tid - d] : 0);
        buf[src ^ 1][tid] = x;
        __syncthreads();
        src ^= 1;
    }
    int run = (tid == 0) ? 0 : buf[src][tid - 1];
    for (int i = 0; i < CPB; ++i) {
        int b = base + i;
        if (b < NCELL) {
            int v = counts2[b];
            offsets2[b] = run;
            cursors2[b] = run;
            run += v;
        }
    }
    if (tid == 255) offsets2[NCELL] = run;
}

__global__ __launch_bounds__(256) void ScatterNL_fillPos2(
    const int* __restrict__ qinds, int Q, int* __restrict__ cursors2,
    int* __restrict__ posOf)
{
    int stride = gridDim.x * blockDim.x;
    for (int q = blockIdx.x * blockDim.x + threadIdx.x; q < Q; q += stride) {
        int t = qinds[3*q], h = qinds[3*q+1], w = qinds[3*q+2];
        int sh = h / TILE, sw = w / TILE;
        int cell = ((t * NBH + sh) * NBW + sw) * TILE + (h - sh * TILE);
        posOf[q] = atomicAdd(&cursors2[cell], 1);
    }
}

// Sequential patch read, scatter-write of contiguous 1216B chunks to
// (bin,dh)-sorted slots. meta (dh|dw<<6) embedded at float index 294.
__global__ __launch_bounds__(256) void ScatterNL_reorder(
    const float* __restrict__ patches, const int* __restrict__ qinds,
    const int* __restrict__ posOf, int Q, float* __restrict__ reord)
{
    int gw   = (blockIdx.x * blockDim.x + threadIdx.x) >> 6;
    int lane = threadIdx.x & 63;
    int nw   = (gridDim.x * blockDim.x) >> 6;
    const bool tail = (lane < ELEM_PER_Q - 256);   // lane < 38
    for (int q0 = 2 * gw; q0 < Q; q0 += 2 * nw) {
        bool two = (q0 + 1 < Q);
        int p0 = posOf[q0];
        int p1 = two ? posOf[q0 + 1] : p0;
        int h0 = qinds[3*q0+1], w0 = qinds[3*q0+2];
        int h1 = two ? qinds[3*q0+4] : 0, w1 = two ? qinds[3*q0+5] : 0;
        const float* s0 = patches + (size_t)q0 * ELEM_PER_Q;
        const float* s1 = s0 + ELEM_PER_Q;
        float a0 = s0[lane], a1 = s0[lane+64], a2 = s0[lane+128], a3 = s0[lane+192];
        float a4 = tail ? s0[lane+256] : 0.f;
        float b0 = 0.f, b1 = 0.f, b2 = 0.f, b3 = 0.f, b4 = 0.f;
        if (two) {
            b0 = s1[lane]; b1 = s1[lane+64]; b2 = s1[lane+128]; b3 = s1[lane+192];
            b4 = tail ? s1[lane+256] : 0.f;
        }
        __builtin_amdgcn_sched_barrier(0);         // keep load cluster together
        float* d0 = reord + (size_t)p0 * STRIDE_F;
        d0[lane] = a0; d0[lane+64] = a1; d0[lane+128] = a2; d0[lane+192] = a3;
        if (tail) d0[lane+256] = a4;
        if (lane == 0)
            d0[294] = __int_as_float((h0 % TILE) | ((w0 % TILE) << 6));
        if (two) {
            float* d1 = reord + (size_t)p1 * STRIDE_F;
            d1[lane] = b0; d1[lane+64] = b1; d1[lane+128] = b2; d1[lane+192] = b3;
            if (tail) d1[lane+256] = b4;
            if (lane == 0)
                d1[294] = __int_as_float((h1 % TILE) | ((w1 % TILE) << 6));
        }
    }
}

// out = vid (gather then atomically adds patch contributions)
__global__ __launch_bounds__(256) void ScatterNL_copy(
    const float* __restrict__ vid, float* __restrict__ out, int n4)
{
    int stride = gridDim.x * blockDim.x;
    const float4* src = (const float4*)vid;
    float4* dst = (float4*)out;
    for (int i = blockIdx.x * blockDim.x + threadIdx.x; i < n4; i += stride)
        dst[i] = src[i];
}

// Gather accum: block = (t-pair k, bh, bw). Two phases (slice 2k, 2k+1).
// Per phase, two (bin,dt) streams feed the slice. Patch-halves are staged
// chunk-by-chunk into LDS (double-buffered, prefetch ahead); each wave owns
// rows {wv+8j}, lane = x pixel; dh-sorted cells give exact per-row candidate
// segments; accumulation is in REGISTERS (no LDS atomics anywhere).
__global__ __launch_bounds__(512) void ScatterNL_gather(
    const float* __restrict__ reord, const int* __restrict__ offsets2,
    const float* __restrict__ vid, float* __restrict__ out)
{
    constexpr int CHUNK = 32;               // staged halves per chunk
    constexpr int SLOT  = 148;              // 147 payload + meta
    __shared__ float stg[2][CHUNK * SLOT];  // 37,888 B
    __shared__ int cellOff[TILE + 1];       // 39 ints

    int bid = blockIdx.x;
    int k   = bid / (NBH * NBW);            // t-pair 0..4
    int r   = bid % (NBH * NBW);
    int bh  = r / NBW, bw = r % NBW;
    int h0  = bh * TILE, w0 = bw * TILE;
    int He  = min(HTILE, H_DIM - h0);
    int We  = min(HTILE, W_DIM - w0);

    const int lane = threadIdx.x & 63;      // x pixel (valid < 44)
    const int wv   = threadIdx.x >> 6;      // 0..7, owns rows wv+8j

    float r4[4][3];                         // staging regs: 4 halves per wave

    auto LOADS = [&](int c0, int E, int dtOff) {
        #pragma unroll
        for (int u = 0; u < 4; ++u) {
            int g = c0 + wv * 4 + u;
            if (g < E) {
                const float* s = reord + (size_t)g * STRIDE_F + dtOff;
                r4[u][0] = s[lane];
                r4[u][1] = s[lane + 64];
                r4[u][2] = (lane < 19) ? s[lane + 128]
                         : (lane == 19) ? reord[(size_t)g * STRIDE_F + 294] : 0.f;
            }
        }
        __builtin_amdgcn_sched_barrier(0);  // pin load issue above compute
    };
    auto WRITES = [&](int c0, int E, int b) {
        #pragma unroll
        for (int u = 0; u < 4; ++u) {
            int g = c0 + wv * 4 + u;
            if (g < E) {
                float* d = &stg[b][(wv * 4 + u) * SLOT];
                d[lane] = r4[u][0];
                d[lane + 64] = r4[u][1];
                if (lane < 19) d[lane + 128] = r4[u][2];
                else if (lane == 19) d[147] = r4[u][2];
            }
        }
    };

    for (int sl = 0; sl < 2; ++sl) {
        float acc[6][3];
        #pragma unroll
        for (int j = 0; j < 6; ++j) {
            acc[j][0] = 0.f; acc[j][1] = 0.f; acc[j][2] = 0.f;
        }

        for (int si = 0; si < 2; ++si) {
            int tb = (si == 0) ? 2 * k : (sl == 0 ? 2 * k - 1 : 2 * k + 1);
            int dt = (si == 0) ? sl   : (sl == 0 ? 1 : 0);
            if (tb < 0 || tb > T_DIM - PT) continue;
            int bin = (tb * NBH + bh) * NBW + bw;
            int dtOff = dt * HALF;

            if (threadIdx.x < TILE + 1)
                cellOff[threadIdx.x] = offsets2[bin * TILE + threadIdx.x];
            __syncthreads();                 // cellOff ready; stg safe to reuse
            int S = cellOff[0], E = cellOff[TILE];
            if (S == E) continue;            // uniform across block

            LOADS(S, E, dtOff);
            WRITES(S, E, 0);
            __syncthreads();                 // chunk 0 staged

            int nb = 0;
            for (int c0 = S; c0 < E; c0 += CHUNK, nb ^= 1) {
                int c1 = min(c0 + CHUNK, E);
                bool more = (c1 < E);
                if (more) LOADS(c0 + CHUNK, E, dtOff);

                // ---- process chunk [c0,c1) from stg[nb] ----
                const float* sb = stg[nb];
                #pragma unroll
                for (int j = 0; j < 6; ++j) {
                    int y = wv + 8 * j;              // 0..47
                    int loI = y - 6; if (loI < 0) loI = 0; if (loI > TILE) loI = TILE;
                    int hiI = (y < TILE) ? y + 1 : TILE;
                    int a = cellOff[loI]; if (a < c0) a = c0;
                    int b2 = cellOff[hiI]; if (b2 > c1) b2 = c1;
                    for (int g = a; g < b2; ++g) {
                        int mb = (g - c0) * SLOT;
                        int meta = __float_as_int(sb[mb + 147]); // uniform -> bcast
                        int dh = meta & 63, dw = (meta >> 6) & 63;
                        int dy = y - dh;             // in [0,6] by construction
                        int dx = lane - dw;
                        bool hit = ((unsigned)dx < 7u);
                        int e = mb + dy * 7 + (hit ? dx : 0);
                        float v0 = sb[e], v1 = sb[e + 49], v2 = sb[e + 98];
                        if (hit) {
                            acc[j][0] += v0; acc[j][1] += v1; acc[j][2] += v2;
                        }
                    }
                }

                if (more) WRITES(c0 + CHUNK, E, nb ^ 1);
                __syncthreads();
            }
        }

        // ---- write-out slice (out pre-filled with vid; halo overlaps -> atomic)
        int ts = 2 * k + sl;
        #pragma unroll
        for (int j = 0; j < 6; ++j) {
            int y = wv + 8 * j;
            if (y < He && lane < We) {
                size_t o = (((size_t)ts * C_DIM) * H_DIM + (h0 + y)) * W_DIM + w0 + lane;
                atomicAdd(&out[o], acc[j][0]);
                atomicAdd(&out[o + (size_t)H_DIM * W_DIM], acc[j][1]);
                atomicAdd(&out[o + 2 * (size_t)H_DIM * W_DIM], acc[j][2]);
            }
        }
    }
}

// ---------------- Fallback path (R2, proven) for small ws_size ----------------

__global__ __launch_bounds__(256) void ScatterNL_hist(
    const int* __restrict__ qinds, int Q, int* __restrict__ counts)
{
    __shared__ int hloc[NBINS];
    for (int i = threadIdx.x; i < NBINS; i += blockDim.x) hloc[i] = 0;
    __syncthreads();
    int stride = gridDim.x * blockDim.x;
    for (int q = blockIdx.x * blockDim.x + threadIdx.x; q < Q; q += stride) {
        int t = qinds[3*q], h = qinds[3*q+1], w = qinds[3*q+2];
        int b = (t * NBH + h / TILE) * NBW + w / TILE;
        atomicAdd(&hloc[b], 1);
    }
    __syncthreads();
    for (int i = threadIdx.x; i < NBINS; i += blockDim.x)
        if (hloc[i]) atomicAdd(&counts[i], hloc[i]);
}

__global__ __launch_bounds__(256) void ScatterNL_scan(
    const int* __restrict__ counts, int* __restrict__ offsets,
    int* __restrict__ cursors)
{
    __shared__ int buf[2][256];
    int tid = threadIdx.x;
    int base = tid * 7;
    int loc[7];
    int s = 0;
    #pragma unroll
    for (int i = 0; i < 7; ++i) {
        int b = base + i;
        int v = (b < NBINS) ? counts[b] : 0;
        loc[i] = s;
        s += v;
    }
    buf[0][tid] = s;
    __syncthreads();
    int src = 0;
    for (int d = 1; d < 256; d <<= 1) {
        int x = buf[src][tid] + ((tid >= d) ? buf[src][tid - d] : 0);
        buf[src ^ 1][tid] = x;
        __syncthreads();
        src ^= 1;
    }
    int excl = (tid == 0) ? 0 : buf[src][tid - 1];
    #pragma unroll
    for (int i = 0; i < 7; ++i) {
        int b = base + i;
        if (b < NBINS) {
            offsets[b] = excl + loc[i];
            cursors[b] = excl + loc[i];
        }
    }
    if (tid == 255) offsets[NBINS] = buf[src][255];
}

__global__ __launch_bounds__(256) void ScatterNL_fillList(
    const int* __restrict__ qinds, int Q, int* __restrict__ cursors,
    int* __restrict__ list)
{
    int stride = gridDim.x * blockDim.x;
    for (int q = blockIdx.x * blockDim.x + threadIdx.x; q < Q; q += stride) {
        int t = qinds[3*q], h = qinds[3*q+1], w = qinds[3*q+2];
        int sh = h / TILE, sw = w / TILE;
        int b = (t * NBH + sh) * NBW + sw;
        int pos = atomicAdd(&cursors[b], 1);
        list[pos] = q | ((h - sh * TILE) << 18) | ((w - sw * TILE) << 24);
    }
}

__global__ __launch_bounds__(512, 6) void ScatterNL_accumList(
    const float* __restrict__ patches, const int* __restrict__ offsets,
    const int* __restrict__ list, float* __restrict__ out)
{
    __shared__ float acc[2 * ACC_SLICE];
    int bid = blockIdx.x;
    int k   = bid / (NBH * NBW);
    int r   = bid % (NBH * NBW);
    int bh  = r / NBW, bw = r % NBW;
    int h0  = bh * TILE, w0 = bw * TILE;
    for (int i = threadIdx.x; i < 2 * ACC_SLICE; i += blockDim.x) acc[i] = 0.f;
    __syncthreads();
    const int lane = threadIdx.x & 63;
    const int wv   = threadIdx.x >> 6;
    int off3[3];
    #pragma unroll
    for (int s = 0; s < 3; ++s) {
        int kx = lane + 64 * s;
        int kk = (kx < HALF) ? kx : 0;
        int c = kk / 49, rr = kk % 49;
        off3[s] = (c * HTILE + rr / 7) * HTILE + rr % 7;
    }
    const bool v2ok = (lane < HALF - 128);
    int offf[5];
    #pragma unroll
    for (int s = 0; s < 5; ++s) {
        int kx = lane + 64 * s;
        int kk = (kx < ELEM_PER_Q) ? kx : 0;
        int sl = kk / HALF;
        int rem = kk % HALF;
        int c = rem / 49, rr = rem % 49;
        offf[s] = sl * ACC_SLICE + (c * HTILE + rr / 7) * HTILE + rr % 7;
    }
    const bool v4ok = (lane < ELEM_PER_Q - 256);
    auto procHalf = [&](int bin, int dtOff, int ss) {
        int start = offsets[bin], n = offsets[bin + 1] - start;
        int sbase = ss * ACC_SLICE;
        for (int base = wv * 4; base < n; base += 32) {
            int i0 = start + base;
            int nb = n - base;
            int e0 = list[i0];
            int e1 = (nb > 1) ? list[i0 + 1] : e0;
            int e2 = (nb > 2) ? list[i0 + 2] : e0;
            int e3 = (nb > 3) ? list[i0 + 3] : e0;
            const float* B0 = patches + (size_t)(e0 & 0x3FFFF) * ELEM_PER_Q + dtOff;
            const float* B1 = patches + (size_t)(e1 & 0x3FFFF) * ELEM_PER_Q + dtOff;
            const float* B2 = patches + (size_t)(e2 & 0x3FFFF) * ELEM_PER_Q + dtOff;
            const float* B3 = patches + (size_t)(e3 & 0x3FFFF) * ELEM_PER_Q + dtOff;
            float a00 = B0[lane], a01 = B0[lane+64], a02 = v2ok ? B0[lane+128] : 0.f;
            float a10 = B1[lane], a11 = B1[lane+64], a12 = v2ok ? B1[lane+128] : 0.f;
            float a20 = B2[lane], a21 = B2[lane+64], a22 = v2ok ? B2[lane+128] : 0.f;
            float a30 = B3[lane], a31 = B3[lane+64], a32 = v2ok ? B3[lane+128] : 0.f;
            __builtin_amdgcn_sched_barrier(0);
            int d0 = sbase + ((e0 >> 18) & 63) * HTILE + ((e0 >> 24) & 63);
            int d1 = sbase + ((e1 >> 18) & 63) * HTILE + ((e1 >> 24) & 63);
            int d2 = sbase + ((e2 >> 18) & 63) * HTILE + ((e2 >> 24) & 63);
            int d3 = sbase + ((e3 >> 18) & 63) * HTILE + ((e3 >> 24) & 63);
            atomicAdd(&acc[d0 + off3[0]], a00);
            atomicAdd(&acc[d0 + off3[1]], a01);
            if (v2ok) atomicAdd(&acc[d0 + off3[2]], a02);
            if (nb > 1) {
                atomicAdd(&acc[d1 + off3[0]], a10);
                atomicAdd(&acc[d1 + off3[1]], a11);
                if (v2ok) atomicAdd(&acc[d1 + off3[2]], a12);
            }
            if (nb > 2) {
                atomicAdd(&acc[d2 + off3[0]], a20);
                atomicAdd(&acc[d2 + off3[1]], a21);
                if (v2ok) atomicAdd(&acc[d2 + off3[2]], a22);
            }
            if (nb > 3) {
                atomicAdd(&acc[d3 + off3[0]], a30);
                atomicAdd(&acc[d3 + off3[1]], a31);
                if (v2ok) atomicAdd(&acc[d3 + off3[2]], a32);
            }
        }
    };
    {
        int bin = (2 * k * NBH + bh) * NBW + bw;
        int start = offsets[bin], n = offsets[bin + 1] - start;
        for (int base = wv * 2; base < n; base += 16) {
            int i0 = start + base;
            int nb = n - base;
            int e0 = list[i0];
            int e1 = (nb > 1) ? list[i0 + 1] : e0;
            const float* B0 = patches + (size_t)(e0 & 0x3FFFF) * ELEM_PER_Q;
            const float* B1 = patches + (size_t)(e1 & 0x3FFFF) * ELEM_PER_Q;
            float a0[5], a1[5];
            #pragma unroll
            for (int s = 0; s < 5; ++s) {
                bool v = (s < 4) || v4ok;
                a0[s] = v ? B0[lane + 64*s] : 0.f;
                a1[s] = v ? B1[lane + 64*s] : 0.f;
            }
            __builtin_amdgcn_sched_barrier(0);
            int d0 = ((e0 >> 18) & 63) * HTILE + ((e0 >> 24) & 63);
            int d1 = ((e1 >> 18) & 63) * HTILE + ((e1 >> 24) & 63);
            #pragma unroll
            for (int s = 0; s < 5; ++s)
                if ((s < 4) || v4ok) atomicAdd(&acc[d0 + offf[s]], a0[s]);
            if (nb > 1) {
                #pragma unroll
                for (int s = 0; s < 5; ++s)
                    if ((s < 4) || v4ok) atomicAdd(&acc[d1 + offf[s]], a1[s]);
            }
        }
    }
    if (2 * k + 1 <= T_DIM - PT)
        procHalf(((2 * k + 1) * NBH + bh) * NBW + bw, 0, 1);
    if (2 * k - 1 >= 0)
        procHalf(((2 * k - 1) * NBH + bh) * NBW + bw, HALF, 0);
    __syncthreads();
    int He = min(HTILE, H_DIM - h0);
    int We = min(HTILE, W_DIM - w0);
    for (int ls = 0; ls < 2; ++ls) {
        int ts = 2 * k + ls;
        #pragma unroll
        for (int c = 0; c < C_DIM; ++c) {
            for (int y = wv; y < He; y += 8) {
                if (lane < We) {
                    float v = acc[(ls * C_DIM + c) * HTILE * HTILE + y * HTILE + lane];
                    size_t o = (((size_t)ts * C_DIM + c) * H_DIM + (h0 + y)) * W_DIM + w0 + lane;
                    atomicAdd(&out[o], v);
                }
            }
        }
    }
}

extern "C" void kernel_launch(void* const* d_in, const int* in_sizes, int n_in,
                              void* d_out, int out_size, void* d_ws, size_t ws_size,
                              hipStream_t stream) {
    const float* vid     = (const float*)d_in[0];
    const float* patches = (const float*)d_in[1];
    const int*   qinds   = (const int*)d_in[2];
    float* out = (float*)d_out;
    int Q = in_sizes[2] / 3;

    int* ws = (int*)d_ws;

    size_t metaInts = (size_t)(3 * CELLPAD) + (size_t)Q;
    size_t reordOff = (metaInts * sizeof(int) + 255) & ~(size_t)255;
    size_t need     = reordOff + (size_t)Q * STRIDE_F * sizeof(float);

    ScatterNL_copy<<<1024, 256, 0, stream>>>(vid, out,
        T_DIM * C_DIM * H_DIM * W_DIM / 4);

    if (ws_size >= need) {
        int* counts2  = ws;
        int* offsets2 = ws + CELLPAD;
        int* cursors2 = ws + 2 * CELLPAD;
        int* posOf    = ws + 3 * CELLPAD;
        float* reord  = (float*)((char*)d_ws + reordOff);

        hipMemsetAsync(counts2, 0, CELLPAD * sizeof(int), stream);
        ScatterNL_hist2<<<256, 256, 0, stream>>>(qinds, Q, counts2);
        ScatterNL_scan2<<<1, 256, 0, stream>>>(counts2, offsets2, cursors2);
        ScatterNL_fillPos2<<<256, 256, 0, stream>>>(qinds, Q, cursors2, posOf);
        ScatterNL_reorder<<<2048, 256, 0, stream>>>(patches, qinds, posOf, Q, reord);
        ScatterNL_gather<<<NPAIR * NBH * NBW, 512, 0, stream>>>(
            reord, offsets2, vid, out);
    } else {
        int* counts  = ws;
        int* offsets = ws + BINPAD;
        int* cursors = ws + 2 * BINPAD;
        int* list    = ws + 3 * BINPAD;
        hipMemsetAsync(counts, 0, BINPAD * sizeof(int), stream);
        ScatterNL_hist<<<256, 256, 0, stream>>>(qinds, Q, counts);
        ScatterNL_scan<<<1, 256, 0, stream>>>(counts, offsets, cursors);
        ScatterNL_fillList<<<256, 256, 0, stream>>>(qinds, Q, cursors, list);
        ScatterNL_accumList<<<NPAIR * NBH * NBW, 512, 0, stream>>>(
            patches, offsets, list, out);
    }
}

// Round 5
// 688.889 us; speedup vs baseline: 1.4569x; 1.3293x over previous
//
#include <hip/hip_runtime.h>

// Problem constants (fixed by reference setup_inputs)
constexpr int T_DIM = 10, C_DIM = 3, H_DIM = 512, W_DIM = 512;
constexpr int PT = 2, PS = 7;
constexpr int ELEM_PER_Q = PT * C_DIM * PS * PS;  // 294
constexpr int HALF      = C_DIM * PS * PS;        // 147 (one dt-slice of a patch)
constexpr int TILE = 38;                           // anchor bin & output tile (h,w)
constexpr int NBH = 14, NBW = 14;                  // ceil(506/38)=14
constexpr int NTB = T_DIM - PT + 1;                // 9 anchor t values
constexpr int NBINS = NTB * NBH * NBW;             // 1764
constexpr int BINPAD = 2048;
constexpr int HTILE = TILE + PS - 1;               // 44: tile + down-right halo
constexpr int ACC_SLICE = C_DIM * HTILE * HTILE;   // (fallback path)
constexpr int NPAIR = T_DIM / 2;                   // 5 t-pairs
constexpr int NCELL = NBINS * TILE;                // 67032 (bin, dh) cells
constexpr int CELLPAD = 67136;                     // padded cell-table stride (ints)
constexpr int SCAN_B = 131;                        // 131 * 512 = 67072 >= NCELL

// ws layout (gather path): counts2[CELLPAD] | offsets2[CELLPAD] | cursors2[CELLPAD] |
//   bsum[256] | list[Q]
// list entry: q[0,18) | dh[18,24) | dw[24,30)   (cell-sorted by (bin,dh))
// ws layout (fallback): counts[2048] | offsets[2048] | cursors[2048] | list[Q]

// ---------------- (bin,dh) histogram ----------------

__global__ __launch_bounds__(256) void ScatterNL_hist2(
    const int* __restrict__ qinds, int Q, int* __restrict__ counts2)
{
    int stride = gridDim.x * blockDim.x;
    for (int q = blockIdx.x * blockDim.x + threadIdx.x; q < Q; q += stride) {
        int t = qinds[3*q], h = qinds[3*q+1], w = qinds[3*q+2];
        int sh = h / TILE, sw = w / TILE;
        int cell = ((t * NBH + sh) * NBW + sw) * TILE + (h - sh * TILE);
        atomicAdd(&counts2[cell], 1);
    }
}

// ---------------- hierarchical scan: A (block sums), B (scan sums), C (emit) ---

__global__ __launch_bounds__(256) void ScatterNL_scanA(
    const int* __restrict__ counts2, int* __restrict__ bsum)
{
    __shared__ int red[256];
    int b = blockIdx.x, tid = threadIdx.x;
    int base = b * 512;
    int c0 = base + tid, c1 = base + 256 + tid;
    int s = ((c0 < NCELL) ? counts2[c0] : 0) + ((c1 < NCELL) ? counts2[c1] : 0);
    red[tid] = s;
    __syncthreads();
    for (int d = 128; d > 0; d >>= 1) {
        if (tid < d) red[tid] += red[tid + d];
        __syncthreads();
    }
    if (tid == 0) bsum[b] = red[0];
}

__global__ __launch_bounds__(256) void ScatterNL_scanB(
    int* __restrict__ bsum, int* __restrict__ offsets2)
{
    __shared__ int buf[2][256];
    int tid = threadIdx.x;
    int v = (tid < SCAN_B) ? bsum[tid] : 0;
    buf[0][tid] = v;
    __syncthreads();
    int src = 0;
    for (int d = 1; d < 256; d <<= 1) {
        int x = buf[src][tid] + ((tid >= d) ? buf[src][tid - d] : 0);
        buf[src ^ 1][tid] = x;
        __syncthreads();
        src ^= 1;
    }
    if (tid < SCAN_B) bsum[tid] = buf[src][tid] - v;   // exclusive base
    if (tid == 255) offsets2[NCELL] = buf[src][SCAN_B - 1];
}

__global__ __launch_bounds__(256) void ScatterNL_scanC(
    const int* __restrict__ counts2, const int* __restrict__ bsum,
    int* __restrict__ offsets2, int* __restrict__ cursors2)
{
    __shared__ int buf[2][256];
    int b = blockIdx.x, tid = threadIdx.x;
    int base = b * 512;
    int c0 = base + 2 * tid, c1 = c0 + 1;
    int v0 = (c0 < NCELL) ? counts2[c0] : 0;
    int v1 = (c1 < NCELL) ? counts2[c1] : 0;
    buf[0][tid] = v0 + v1;
    __syncthreads();
    int src = 0;
    for (int d = 1; d < 256; d <<= 1) {
        int x = buf[src][tid] + ((tid >= d) ? buf[src][tid - d] : 0);
        buf[src ^ 1][tid] = x;
        __syncthreads();
        src ^= 1;
    }
    int excl = bsum[b] + ((tid == 0) ? 0 : buf[src][tid - 1]);
    if (c0 < NCELL) { offsets2[c0] = excl;      cursors2[c0] = excl; }
    if (c1 < NCELL) { offsets2[c1] = excl + v0; cursors2[c1] = excl + v0; }
}

__global__ __launch_bounds__(256) void ScatterNL_fillList2(
    const int* __restrict__ qinds, int Q, int* __restrict__ cursors2,
    int* __restrict__ list)
{
    int stride = gridDim.x * blockDim.x;
    for (int q = blockIdx.x * blockDim.x + threadIdx.x; q < Q; q += stride) {
        int t = qinds[3*q], h = qinds[3*q+1], w = qinds[3*q+2];
        int sh = h / TILE, sw = w / TILE;
        int dh = h - sh * TILE, dw = w - sw * TILE;
        int cell = ((t * NBH + sh) * NBW + sw) * TILE + dh;
        int pos = atomicAdd(&cursors2[cell], 1);
        list[pos] = q | (dh << 18) | (dw << 24);
    }
}

// out = vid (gather then atomically adds patch contributions)
__global__ __launch_bounds__(256) void ScatterNL_copy(
    const float* __restrict__ vid, float* __restrict__ out, int n4)
{
    int stride = gridDim.x * blockDim.x;
    const float4* src = (const float4*)vid;
    float4* dst = (float4*)out;
    for (int i = blockIdx.x * blockDim.x + threadIdx.x; i < n4; i += stride)
        dst[i] = src[i];
}

// Direct gather: identical consumer structure to R4's winner, but staging
// reads patch-halves straight from `patches` (random 588B granules) using
// the cell-sorted index list. Meta (dh,dw) comes free from the list entry.
__global__ __launch_bounds__(512) void ScatterNL_gatherD(
    const float* __restrict__ patches, const int* __restrict__ list,
    const int* __restrict__ offsets2, float* __restrict__ out)
{
    constexpr int CHUNK = 32;               // staged halves per chunk
    constexpr int SLOT  = 148;              // 147 payload + meta
    __shared__ float stg[2][CHUNK * SLOT];  // 37,888 B
    __shared__ int cellOff[TILE + 1];       // 39 ints

    int bid = blockIdx.x;
    int k   = bid / (NBH * NBW);            // t-pair 0..4
    int r   = bid % (NBH * NBW);
    int bh  = r / NBW, bw = r % NBW;
    int h0  = bh * TILE, w0 = bw * TILE;
    int He  = min(HTILE, H_DIM - h0);
    int We  = min(HTILE, W_DIM - w0);

    const int lane = threadIdx.x & 63;      // x pixel (valid < 44)
    const int wv   = threadIdx.x >> 6;      // 0..7, owns rows wv+8j

    float r4[4][3];                         // staging regs: 4 halves per wave

    auto LOADS = [&](int c0, int E, int dtOff) {
        #pragma unroll
        for (int u = 0; u < 4; ++u) {
            int g = c0 + wv * 4 + u;
            if (g < E) {
                int ent = list[g];          // uniform address -> broadcast
                const float* s = patches + (size_t)(ent & 0x3FFFF) * ELEM_PER_Q + dtOff;
                r4[u][0] = s[lane];
                r4[u][1] = s[lane + 64];
                r4[u][2] = (lane < 19) ? s[lane + 128]
                         : (lane == 19) ? __int_as_float(ent >> 18) : 0.f;
            }
        }
        __builtin_amdgcn_sched_barrier(0);  // pin load issue above compute
    };
    auto WRITES = [&](int c0, int E, int b) {
        #pragma unroll
        for (int u = 0; u < 4; ++u) {
            int g = c0 + wv * 4 + u;
            if (g < E) {
                float* d = &stg[b][(wv * 4 + u) * SLOT];
                d[lane] = r4[u][0];
                d[lane + 64] = r4[u][1];
                if (lane < 19) d[lane + 128] = r4[u][2];
                else if (lane == 19) d[147] = r4[u][2];
            }
        }
    };

    for (int sl = 0; sl < 2; ++sl) {
        float acc[6][3];
        #pragma unroll
        for (int j = 0; j < 6; ++j) {
            acc[j][0] = 0.f; acc[j][1] = 0.f; acc[j][2] = 0.f;
        }

        for (int si = 0; si < 2; ++si) {
            int tb = (si == 0) ? 2 * k : (sl == 0 ? 2 * k - 1 : 2 * k + 1);
            int dt = (si == 0) ? sl   : (sl == 0 ? 1 : 0);
            if (tb < 0 || tb > T_DIM - PT) continue;
            int bin = (tb * NBH + bh) * NBW + bw;
            int dtOff = dt * HALF;

            if (threadIdx.x < TILE + 1)
                cellOff[threadIdx.x] = offsets2[bin * TILE + threadIdx.x];
            __syncthreads();                 // cellOff ready; stg safe to reuse
            int S = cellOff[0], E = cellOff[TILE];
            if (S == E) continue;            // uniform across block

            LOADS(S, E, dtOff);
            WRITES(S, E, 0);
            __syncthreads();                 // chunk 0 staged

            int nb = 0;
            for (int c0 = S; c0 < E; c0 += CHUNK, nb ^= 1) {
                int c1 = min(c0 + CHUNK, E);
                bool more = (c1 < E);
                if (more) LOADS(c0 + CHUNK, E, dtOff);

                // ---- process chunk [c0,c1) from stg[nb] ----
                const float* sb = stg[nb];
                #pragma unroll
                for (int j = 0; j < 6; ++j) {
                    int y = wv + 8 * j;              // 0..47
                    int loI = y - 6; if (loI < 0) loI = 0; if (loI > TILE) loI = TILE;
                    int hiI = (y < TILE) ? y + 1 : TILE;
                    int a = cellOff[loI]; if (a < c0) a = c0;
                    int b2 = cellOff[hiI]; if (b2 > c1) b2 = c1;
                    for (int g = a; g < b2; ++g) {
                        int mb = (g - c0) * SLOT;
                        int meta = __float_as_int(sb[mb + 147]); // uniform -> bcast
                        int dh = meta & 63, dw = (meta >> 6) & 63;
                        int dy = y - dh;             // in [0,6] by construction
                        int dx = lane - dw;
                        bool hit = ((unsigned)dx < 7u);
                        int e = mb + dy * 7 + (hit ? dx : 0);
                        float v0 = sb[e], v1 = sb[e + 49], v2 = sb[e + 98];
                        if (hit) {
                            acc[j][0] += v0; acc[j][1] += v1; acc[j][2] += v2;
                        }
                    }
                }

                if (more) WRITES(c0 + CHUNK, E, nb ^ 1);
                __syncthreads();
            }
        }

        // ---- write-out slice (out pre-filled with vid; halo overlaps -> atomic)
        int ts = 2 * k + sl;
        #pragma unroll
        for (int j = 0; j < 6; ++j) {
            int y = wv + 8 * j;
            if (y < He && lane < We) {
                size_t o = (((size_t)ts * C_DIM) * H_DIM + (h0 + y)) * W_DIM + w0 + lane;
                atomicAdd(&out[o], acc[j][0]);
                atomicAdd(&out[o + (size_t)H_DIM * W_DIM], acc[j][1]);
                atomicAdd(&out[o + 2 * (size_t)H_DIM * W_DIM], acc[j][2]);
            }
        }
    }
}

// ---------------- Fallback path (R2, proven) for small ws_size ----------------

__global__ __launch_bounds__(256) void ScatterNL_hist(
    const int* __restrict__ qinds, int Q, int* __restrict__ counts)
{
    __shared__ int hloc[NBINS];
    for (int i = threadIdx.x; i < NBINS; i += blockDim.x) hloc[i] = 0;
    __syncthreads();
    int stride = gridDim.x * blockDim.x;
    for (int q = blockIdx.x * blockDim.x + threadIdx.x; q < Q; q += stride) {
        int t = qinds[3*q], h = qinds[3*q+1], w = qinds[3*q+2];
        int b = (t * NBH + h / TILE) * NBW + w / TILE;
        atomicAdd(&hloc[b], 1);
    }
    __syncthreads();
    for (int i = threadIdx.x; i < NBINS; i += blockDim.x)
        if (hloc[i]) atomicAdd(&counts[i], hloc[i]);
}

__global__ __launch_bounds__(256) void ScatterNL_scan(
    const int* __restrict__ counts, int* __restrict__ offsets,
    int* __restrict__ cursors)
{
    __shared__ int buf[2][256];
    int tid = threadIdx.x;
    int base = tid * 7;
    int loc[7];
    int s = 0;
    #pragma unroll
    for (int i = 0; i < 7; ++i) {
        int b = base + i;
        int v = (b < NBINS) ? counts[b] : 0;
        loc[i] = s;
        s += v;
    }
    buf[0][tid] = s;
    __syncthreads();
    int src = 0;
    for (int d = 1; d < 256; d <<= 1) {
        int x = buf[src][tid] + ((tid >= d) ? buf[src][tid - d] : 0);
        buf[src ^ 1][tid] = x;
        __syncthreads();
        src ^= 1;
    }
    int excl = (tid == 0) ? 0 : buf[src][tid - 1];
    #pragma unroll
    for (int i = 0; i < 7; ++i) {
        int b = base + i;
        if (b < NBINS) {
            offsets[b] = excl + loc[i];
            cursors[b] = excl + loc[i];
        }
    }
    if (tid == 255) offsets[NBINS] = buf[src][255];
}

__global__ __launch_bounds__(256) void ScatterNL_fillList(
    const int* __restrict__ qinds, int Q, int* __restrict__ cursors,
    int* __restrict__ list)
{
    int stride = gridDim.x * blockDim.x;
    for (int q = blockIdx.x * blockDim.x + threadIdx.x; q < Q; q += stride) {
        int t = qinds[3*q], h = qinds[3*q+1], w = qinds[3*q+2];
        int sh = h / TILE, sw = w / TILE;
        int b = (t * NBH + sh) * NBW + sw;
        int pos = atomicAdd(&cursors[b], 1);
        list[pos] = q | ((h - sh * TILE) << 18) | ((w - sw * TILE) << 24);
    }
}

__global__ __launch_bounds__(512, 6) void ScatterNL_accumList(
    const float* __restrict__ patches, const int* __restrict__ offsets,
    const int* __restrict__ list, float* __restrict__ out)
{
    __shared__ float acc[2 * ACC_SLICE];
    int bid = blockIdx.x;
    int k   = bid / (NBH * NBW);
    int r   = bid % (NBH * NBW);
    int bh  = r / NBW, bw = r % NBW;
    int h0  = bh * TILE, w0 = bw * TILE;
    for (int i = threadIdx.x; i < 2 * ACC_SLICE; i += blockDim.x) acc[i] = 0.f;
    __syncthreads();
    const int lane = threadIdx.x & 63;
    const int wv   = threadIdx.x >> 6;
    int off3[3];
    #pragma unroll
    for (int s = 0; s < 3; ++s) {
        int kx = lane + 64 * s;
        int kk = (kx < HALF) ? kx : 0;
        int c = kk / 49, rr = kk % 49;
        off3[s] = (c * HTILE + rr / 7) * HTILE + rr % 7;
    }
    const bool v2ok = (lane < HALF - 128);
    int offf[5];
    #pragma unroll
    for (int s = 0; s < 5; ++s) {
        int kx = lane + 64 * s;
        int kk = (kx < ELEM_PER_Q) ? kx : 0;
        int sl = kk / HALF;
        int rem = kk % HALF;
        int c = rem / 49, rr = rem % 49;
        offf[s] = sl * ACC_SLICE + (c * HTILE + rr / 7) * HTILE + rr % 7;
    }
    const bool v4ok = (lane < ELEM_PER_Q - 256);
    auto procHalf = [&](int bin, int dtOff, int ss) {
        int start = offsets[bin], n = offsets[bin + 1] - start;
        int sbase = ss * ACC_SLICE;
        for (int base = wv * 4; base < n; base += 32) {
            int i0 = start + base;
            int nb = n - base;
            int e0 = list[i0];
            int e1 = (nb > 1) ? list[i0 + 1] : e0;
            int e2 = (nb > 2) ? list[i0 + 2] : e0;
            int e3 = (nb > 3) ? list[i0 + 3] : e0;
            const float* B0 = patches + (size_t)(e0 & 0x3FFFF) * ELEM_PER_Q + dtOff;
            const float* B1 = patches + (size_t)(e1 & 0x3FFFF) * ELEM_PER_Q + dtOff;
            const float* B2 = patches + (size_t)(e2 & 0x3FFFF) * ELEM_PER_Q + dtOff;
            const float* B3 = patches + (size_t)(e3 & 0x3FFFF) * ELEM_PER_Q + dtOff;
            float a00 = B0[lane], a01 = B0[lane+64], a02 = v2ok ? B0[lane+128] : 0.f;
            float a10 = B1[lane], a11 = B1[lane+64], a12 = v2ok ? B1[lane+128] : 0.f;
            float a20 = B2[lane], a21 = B2[lane+64], a22 = v2ok ? B2[lane+128] : 0.f;
            float a30 = B3[lane], a31 = B3[lane+64], a32 = v2ok ? B3[lane+128] : 0.f;
            __builtin_amdgcn_sched_barrier(0);
            int d0 = sbase + ((e0 >> 18) & 63) * HTILE + ((e0 >> 24) & 63);
            int d1 = sbase + ((e1 >> 18) & 63) * HTILE + ((e1 >> 24) & 63);
            int d2 = sbase + ((e2 >> 18) & 63) * HTILE + ((e2 >> 24) & 63);
            int d3 = sbase + ((e3 >> 18) & 63) * HTILE + ((e3 >> 24) & 63);
            atomicAdd(&acc[d0 + off3[0]], a00);
            atomicAdd(&acc[d0 + off3[1]], a01);
            if (v2ok) atomicAdd(&acc[d0 + off3[2]], a02);
            if (nb > 1) {
                atomicAdd(&acc[d1 + off3[0]], a10);
                atomicAdd(&acc[d1 + off3[1]], a11);
                if (v2ok) atomicAdd(&acc[d1 + off3[2]], a12);
            }
            if (nb > 2) {
                atomicAdd(&acc[d2 + off3[0]], a20);
                atomicAdd(&acc[d2 + off3[1]], a21);
                if (v2ok) atomicAdd(&acc[d2 + off3[2]], a22);
            }
            if (nb > 3) {
                atomicAdd(&acc[d3 + off3[0]], a30);
                atomicAdd(&acc[d3 + off3[1]], a31);
                if (v2ok) atomicAdd(&acc[d3 + off3[2]], a32);
            }
        }
    };
    {
        int bin = (2 * k * NBH + bh) * NBW + bw;
        int start = offsets[bin], n = offsets[bin + 1] - start;
        for (int base = wv * 2; base < n; base += 16) {
            int i0 = start + base;
            int nb = n - base;
            int e0 = list[i0];
            int e1 = (nb > 1) ? list[i0 + 1] : e0;
            const float* B0 = patches + (size_t)(e0 & 0x3FFFF) * ELEM_PER_Q;
            const float* B1 = patches + (size_t)(e1 & 0x3FFFF) * ELEM_PER_Q;
            float a0[5], a1[5];
            #pragma unroll
            for (int s = 0; s < 5; ++s) {
                bool v = (s < 4) || v4ok;
                a0[s] = v ? B0[lane + 64*s] : 0.f;
                a1[s] = v ? B1[lane + 64*s] : 0.f;
            }
            __builtin_amdgcn_sched_barrier(0);
            int d0 = ((e0 >> 18) & 63) * HTILE + ((e0 >> 24) & 63);
            int d1 = ((e1 >> 18) & 63) * HTILE + ((e1 >> 24) & 63);
            #pragma unroll
            for (int s = 0; s < 5; ++s)
                if ((s < 4) || v4ok) atomicAdd(&acc[d0 + offf[s]], a0[s]);
            if (nb > 1) {
                #pragma unroll
                for (int s = 0; s < 5; ++s)
                    if ((s < 4) || v4ok) atomicAdd(&acc[d1 + offf[s]], a1[s]);
            }
        }
    }
    if (2 * k + 1 <= T_DIM - PT)
        procHalf(((2 * k + 1) * NBH + bh) * NBW + bw, 0, 1);
    if (2 * k - 1 >= 0)
        procHalf(((2 * k - 1) * NBH + bh) * NBW + bw, HALF, 0);
    __syncthreads();
    int He = min(HTILE, H_DIM - h0);
    int We = min(HTILE, W_DIM - w0);
    for (int ls = 0; ls < 2; ++ls) {
        int ts = 2 * k + ls;
        #pragma unroll
        for (int c = 0; c < C_DIM; ++c) {
            for (int y = wv; y < He; y += 8) {
                if (lane < We) {
                    float v = acc[(ls * C_DIM + c) * HTILE * HTILE + y * HTILE + lane];
                    size_t o = (((size_t)ts * C_DIM + c) * H_DIM + (h0 + y)) * W_DIM + w0 + lane;
                    atomicAdd(&out[o], v);
                }
            }
        }
    }
}

extern "C" void kernel_launch(void* const* d_in, const int* in_sizes, int n_in,
                              void* d_out, int out_size, void* d_ws, size_t ws_size,
                              hipStream_t stream) {
    const float* vid     = (const float*)d_in[0];
    const float* patches = (const float*)d_in[1];
    const int*   qinds   = (const int*)d_in[2];
    float* out = (float*)d_out;
    int Q = in_sizes[2] / 3;

    int* ws = (int*)d_ws;

    size_t need = ((size_t)(3 * CELLPAD) + 256 + (size_t)Q) * sizeof(int);

    ScatterNL_copy<<<1024, 256, 0, stream>>>(vid, out,
        T_DIM * C_DIM * H_DIM * W_DIM / 4);

    if (ws_size >= need) {
        int* counts2  = ws;
        int* offsets2 = ws + CELLPAD;
        int* cursors2 = ws + 2 * CELLPAD;
        int* bsum     = ws + 3 * CELLPAD;
        int* list     = ws + 3 * CELLPAD + 256;

        hipMemsetAsync(counts2, 0, CELLPAD * sizeof(int), stream);
        ScatterNL_hist2<<<256, 256, 0, stream>>>(qinds, Q, counts2);
        ScatterNL_scanA<<<SCAN_B, 256, 0, stream>>>(counts2, bsum);
        ScatterNL_scanB<<<1, 256, 0, stream>>>(bsum, offsets2);
        ScatterNL_scanC<<<SCAN_B, 256, 0, stream>>>(counts2, bsum, offsets2, cursors2);
        ScatterNL_fillList2<<<256, 256, 0, stream>>>(qinds, Q, cursors2, list);
        ScatterNL_gatherD<<<NPAIR * NBH * NBW, 512, 0, stream>>>(
            patches, list, offsets2, out);
    } else {
        int* counts  = ws;
        int* offsets = ws + BINPAD;
        int* cursors = ws + 2 * BINPAD;
        int* list    = ws + 3 * BINPAD;
        hipMemsetAsync(counts, 0, BINPAD * sizeof(int), stream);
        ScatterNL_hist<<<256, 256, 0, stream>>>(qinds, Q, counts);
        ScatterNL_scan<<<1, 256, 0, stream>>>(counts, offsets, cursors);
        ScatterNL_fillList<<<256, 256, 0, stream>>>(qinds, Q, cursors, list);
        ScatterNL_accumList<<<NPAIR * NBH * NBW, 512, 0, stream>>>(
            patches, offsets, list, out);
    }
}